// Round 2
// baseline (173.748 us; speedup 1.0000x reference)
//
#include <hip/hip_runtime.h>

#define BDIM 256
#define TILE 64
#define HALO 7
#define IN_T 78           // TILE + 2*HALO rows of h-min
#define LSTR 67           // LDS row stride: bank stride 67%32=3, gcd(3,32)=1 -> conflict-free
#define IMG_H 512
#define IMG_W 512
#define HW (IMG_H * IMG_W)
#define NPIX (16.0f * 512.0f * 512.0f)

typedef float f4 __attribute__((ext_vector_type(4)));

__device__ __forceinline__ int reflect_idx(int i, int n) {
    // np.pad 'reflect' (no edge repeat)
    i = (i < 0) ? -i : i;
    i = (i >= n) ? (2 * n - 2 - i) : i;
    return i;
}

// Horizontal 15-window min for 16 outputs of one row chunk, reading raw
// pixels from global (3 channels, channel-min fused), writing 16 floats
// to LDS at dst[0..15]. Window cols: C0 .. C0+29 (Gil-Werman, 16 out).
__device__ __forceinline__ void hmin_row(const float* __restrict__ X, int gr,
                                         int C0, bool fast,
                                         float* __restrict__ dst) {
    float w[30];
    const float* rowp = X + (size_t)gr * IMG_W;
    if (fast) {
        // C0-1 is a multiple of 4 -> all float4 loads 16B-aligned
        const float* g0 = rowp + (C0 - 1);
        #pragma unroll
        for (int b = 0; b < 8; ++b) {
            f4 a = *(const f4*)(g0 + 4 * b);
            f4 g = *(const f4*)(g0 + HW + 4 * b);
            f4 c = *(const f4*)(g0 + 2 * HW + 4 * b);
            #pragma unroll
            for (int k = 0; k < 4; ++k) {
                int idx = 4 * b + k - 1;           // w index (static)
                if (idx >= 0 && idx < 30)
                    w[idx] = fminf(a[k], fminf(g[k], c[k]));
            }
        }
    } else {
        #pragma unroll
        for (int j = 0; j < 30; ++j) {
            int gc = reflect_idx(C0 + j, IMG_W);
            w[j] = fminf(rowp[gc], fminf(rowp[HW + gc], rowp[2 * HW + gc]));
        }
    }
    // Gil-Werman: suffix-min of first 15, then streaming forward min
    float s[15];
    #pragma unroll
    for (int j = 0; j < 15; ++j) s[j] = w[j];
    #pragma unroll
    for (int j = 13; j >= 0; --j) s[j] = fminf(s[j], s[j + 1]);
    dst[0] = s[0];
    float f = w[15];
    #pragma unroll
    for (int i = 1; i <= 14; ++i) {
        dst[i] = fminf(s[i], f);
        f = fminf(f, w[15 + i]);
    }
    dst[15] = f;
}

// Vertical 15-window min: 16 outputs down one column, from LDS hm.
__device__ __forceinline__ void vmin_col(const float* __restrict__ hm, int col,
                                         int rr0, float (&o)[16]) {
    float s[15];
    #pragma unroll
    for (int j = 0; j < 15; ++j) s[j] = hm[(rr0 + j) * LSTR + col];
    #pragma unroll
    for (int j = 13; j >= 0; --j) s[j] = fminf(s[j], s[j + 1]);
    o[0] = s[0];
    float f = hm[(rr0 + 15) * LSTR + col];
    #pragma unroll
    for (int i = 1; i <= 14; ++i) {
        o[i] = fminf(s[i], f);
        f = fminf(f, hm[(rr0 + 15 + i) * LSTR + col]);
    }
    o[15] = f;
}

__device__ __forceinline__ void dark_tile(const float* __restrict__ X,
                                          float* __restrict__ hm,
                                          int tid, int r0g, int c0blk,
                                          float (&o)[16]) {
    // Phase 1: global -> regs (channel-min + h-min) -> LDS hm[78][LSTR]
    for (int t = tid; t < IN_T * 4; t += BDIM) {
        int chunk = (unsigned)t / IN_T;
        int row = t - chunk * IN_T;
        int C0 = c0blk + chunk * 16;               // first window col (global)
        int gr = reflect_idx(r0g + row, IMG_H);
        bool fast = (C0 >= 1) && (C0 + 30 < IMG_W);
        hmin_row(X, gr, C0, fast, hm + row * LSTR + chunk * 16);
    }
    __syncthreads();
    // Phase 2: vertical 15-min, hm -> 16 regs/thread (exactly 256 tasks)
    vmin_col(hm, tid & 63, (tid >> 6) * 16, o);
}

__global__ __launch_bounds__(BDIM, 4)
void dcl_kernel(const float* __restrict__ real, const float* __restrict__ fake,
                float* __restrict__ out) {
    __shared__ float hm[IN_T * LSTR];   // 20.9 KB -> 4+ blocks/CU, grid all-resident
    __shared__ float red[BDIM / 64];

    const int tid = threadIdx.x;
    const int r0g = blockIdx.y * TILE - HALO;
    const int c0blk = blockIdx.x * TILE - HALO;     // col of window start, chunk 0
    const size_t ib = (size_t)blockIdx.z * 3 * HW;

    float o_r[16], o_f[16];
    dark_tile(real + ib, hm, tid, r0g, c0blk, o_r);
    __syncthreads();                                 // hm reuse: reads done before fake writes
    dark_tile(fake + ib, hm, tid, r0g, c0blk, o_f);

    // map -> clip((v+1)/2, 0, 0.1); MSE partial
    float acc = 0.f;
    #pragma unroll
    for (int i = 0; i < 16; ++i) {
        float a = fminf(fmaxf(0.5f * o_r[i] + 0.5f, 0.f), 0.1f);
        float b = fminf(fmaxf(0.5f * o_f[i] + 0.5f, 0.f), 0.1f);
        float d = a - b;
        acc += d * d;
    }
    #pragma unroll
    for (int off = 32; off >= 1; off >>= 1)
        acc += __shfl_xor(acc, off, 64);
    if ((tid & 63) == 0) red[tid >> 6] = acc;
    __syncthreads();
    if (tid == 0) {
        float t = red[0] + red[1] + red[2] + red[3];
        atomicAdd(out, t * (1.0f / NPIX));
    }
}

extern "C" void kernel_launch(void* const* d_in, const int* in_sizes, int n_in,
                              void* d_out, int out_size, void* d_ws, size_t ws_size,
                              hipStream_t stream) {
    const float* real = (const float*)d_in[0];
    const float* fake = (const float*)d_in[1];
    float* out = (float*)d_out;
    hipMemsetAsync(out, 0, sizeof(float), stream);   // harness poisons d_out
    dim3 grid(IMG_W / TILE, IMG_H / TILE, 16);
    dcl_kernel<<<grid, BDIM, 0, stream>>>(real, fake, out);
}

// Round 3
// 143.456 us; speedup vs baseline: 1.2112x; 1.2112x over previous
//
#include <hip/hip_runtime.h>

#define BDIM 256
#define TILE 64
#define HALO 7
#define IN_T 78            // halo'd tile rows/cols
#define CSTR 84            // cmin row stride (ushort units): 168 B, 8B-aligned rows
#define VSTR 82            // vm row stride (ushort units): 164 B = 41 dwords, gcd(41,32)=1
#define IMG 512
#define HW (IMG * IMG)
#define NPIX (16.0f * 512.0f * 512.0f)
#define P1_TASKS (IN_T * 20)   // 78 rows x 20 float4-groups = 1560
#define P1_ITERS 7

typedef float f4 __attribute__((ext_vector_type(4)));

__device__ __forceinline__ int reflect_idx(int i, int n) {
    i = (i < 0) ? -i : i;
    i = (i >= n) ? (2 * n - 2 - i) : i;
    return i;
}

__device__ __forceinline__ unsigned short umin16(unsigned short a, unsigned short b) {
    return a < b ? a : b;
}

// clip((v+1)/2, 0, 0.1) then f32->bf16 RNE. Non-negative, so bf16 bit pattern
// order == numeric order -> window mins run as u16 integer mins.
__device__ __forceinline__ unsigned short map_bf16(float v) {
    float m = fminf(fmaxf(fmaf(v, 0.5f, 0.5f), 0.0f), 0.1f);
    unsigned int u = __float_as_uint(m);
    return (unsigned short)((u + 0x7fffu + ((u >> 16) & 1u)) >> 16);
}

__device__ __forceinline__ float bf16_f32(unsigned short x) {
    return __uint_as_float(((unsigned int)x) << 16);
}

__device__ __forceinline__ void dark_tile(const float* __restrict__ X,
                                          unsigned short* __restrict__ cmin,
                                          unsigned short* __restrict__ vm,
                                          int tid, int r0g, int c0g, bool fastcol,
                                          float (&o)[16]) {
    // ---- Phase 1: global -> channel-min -> map -> bf16 -> cmin[78 rows][slots 0..79]
    // Physical slot p holds logical col p-1 (global col c0g + p - 1); slots 0,79 = pad.
    #pragma unroll
    for (int i = 0; i < P1_ITERS; ++i) {
        int t = tid + i * BDIM;
        t = t < (P1_TASKS - 1) ? t : (P1_TASKS - 1);   // tail: duplicate last task (benign)
        int row = (unsigned)t / 20u;
        int g = t - row * 20;
        int gr = reflect_idx(r0g + row, IMG);
        const float* rp = X + (size_t)gr * IMG;
        unsigned short w[4];
        if (fastcol) {
            const float* p = rp + (c0g - 1 + 4 * g);   // 16B-aligned for interior blocks
            f4 a = *(const f4*)p;
            f4 b = *(const f4*)(p + HW);
            f4 c = *(const f4*)(p + 2 * HW);
            #pragma unroll
            for (int k = 0; k < 4; ++k)
                w[k] = map_bf16(fminf(a[k], fminf(b[k], c[k])));
        } else {
            #pragma unroll
            for (int k = 0; k < 4; ++k) {
                int gc = reflect_idx(c0g - 1 + 4 * g + k, IMG);
                float v = fminf(rp[gc], fminf(rp[HW + gc], rp[2 * HW + gc]));
                w[k] = map_bf16(v);
            }
        }
        uint2 pk;
        pk.x = (unsigned)w[0] | ((unsigned)w[1] << 16);
        pk.y = (unsigned)w[2] | ((unsigned)w[3] << 16);
        *(uint2*)&cmin[row * CSTR + 4 * g] = pk;       // byte 168*row+8*g: 8B-aligned
    }
    __syncthreads();

    // ---- Phase 2: vertical 15-min (u16), cmin -> vm[64][cols 0..77]
    #pragma unroll
    for (int b = 0; b < 2; ++b) {
        int t = tid + b * BDIM;
        if (t < IN_T * 4) {
            int col = (unsigned)t % (unsigned)IN_T;
            int rr0 = ((unsigned)t / (unsigned)IN_T) * 16;
            const unsigned short* cp = cmin + (col + 1);
            unsigned short s[15];
            #pragma unroll
            for (int j = 0; j < 15; ++j) s[j] = cp[(rr0 + j) * CSTR];
            #pragma unroll
            for (int j = 13; j >= 0; --j) s[j] = umin16(s[j], s[j + 1]);
            unsigned short* vp = vm + col;
            vp[rr0 * VSTR] = s[0];
            unsigned short f = cp[(rr0 + 15) * CSTR];
            #pragma unroll
            for (int i2 = 1; i2 <= 14; ++i2) {
                vp[(rr0 + i2) * VSTR] = umin16(s[i2], f);
                f = umin16(f, cp[(rr0 + 15 + i2) * CSTR]);
            }
            vp[(rr0 + 15) * VSTR] = f;
        }
    }
    __syncthreads();

    // ---- Phase 3: horizontal 15-min (u16) from vm, 16 outputs/thread
    {
        int row = tid >> 2, k = tid & 3;
        const unsigned int* vr = (const unsigned int*)(vm + row * VSTR) + 8 * k;
        unsigned short x[32];
        #pragma unroll
        for (int j = 0; j < 16; ++j) {
            unsigned int d = vr[j];
            x[2 * j] = (unsigned short)d;
            x[2 * j + 1] = (unsigned short)(d >> 16);
        }
        unsigned short s[15];
        #pragma unroll
        for (int j = 0; j < 15; ++j) s[j] = x[j];
        #pragma unroll
        for (int j = 13; j >= 0; --j) s[j] = umin16(s[j], s[j + 1]);
        o[0] = bf16_f32(s[0]);
        unsigned short f = x[15];
        #pragma unroll
        for (int i2 = 1; i2 <= 14; ++i2) {
            o[i2] = bf16_f32(umin16(s[i2], f));
            f = umin16(f, x[15 + i2]);
        }
        o[15] = bf16_f32(f);
    }
}

__global__ __launch_bounds__(BDIM, 4)
void dcl_kernel(const float* __restrict__ real, const float* __restrict__ fake,
                float* __restrict__ out) {
    __shared__ __align__(8) unsigned short cmin[IN_T * CSTR];  // 13.1 KB
    __shared__ __align__(8) unsigned short vm[TILE * VSTR];    // 10.5 KB
    __shared__ float red[BDIM / 64];

    const int tid = threadIdx.x;
    const int r0g = blockIdx.y * TILE - HALO;
    const int c0g = blockIdx.x * TILE - HALO;
    const bool fastcol = (c0g >= 1) && (c0g + 79 <= IMG);
    const size_t ib = (size_t)blockIdx.z * 3 * HW;

    float o_r[16], o_f[16];
    dark_tile(real + ib, cmin, vm, tid, r0g, c0g, fastcol, o_r);
    // no barrier needed: fake's phase-1 writes cmin (guarded by its own barrier
    // before phase 2); vm reads of phase 3 complete before that barrier releases.
    dark_tile(fake + ib, cmin, vm, tid, r0g, c0g, fastcol, o_f);

    float acc = 0.f;
    #pragma unroll
    for (int i = 0; i < 16; ++i) {
        float d = o_r[i] - o_f[i];
        acc += d * d;
    }
    #pragma unroll
    for (int off = 32; off >= 1; off >>= 1)
        acc += __shfl_xor(acc, off, 64);
    if ((tid & 63) == 0) red[tid >> 6] = acc;
    __syncthreads();
    if (tid == 0) {
        float t = red[0] + red[1] + red[2] + red[3];
        atomicAdd(out, t * (1.0f / NPIX));
    }
}

extern "C" void kernel_launch(void* const* d_in, const int* in_sizes, int n_in,
                              void* d_out, int out_size, void* d_ws, size_t ws_size,
                              hipStream_t stream) {
    const float* real = (const float*)d_in[0];
    const float* fake = (const float*)d_in[1];
    float* out = (float*)d_out;
    hipMemsetAsync(out, 0, sizeof(float), stream);   // harness poisons d_out
    dim3 grid(IMG / TILE, IMG / TILE, 16);
    dcl_kernel<<<grid, BDIM, 0, stream>>>(real, fake, out);
}

// Round 4
// 140.139 us; speedup vs baseline: 1.2398x; 1.0237x over previous
//
#include <hip/hip_runtime.h>

#define BDIM 256
#define TILE 64
#define HALO 7
#define IN_T 78            // halo'd tile rows/cols
#define CSTR 84            // cmin row stride (ushort units): 168 B, 8B-aligned rows
#define VSTR 82            // vm row stride (ushort units): 164 B = 41 dwords, gcd(41,32)=1
#define IMG 512
#define HW (IMG * IMG)
#define NPIX (16.0f * 512.0f * 512.0f)
#define P1_TASKS (IN_T * 20)   // 78 rows x 20 float4-groups = 1560
#define P1_ITERS 7
#define NBLOCKS 1024

typedef float f4 __attribute__((ext_vector_type(4)));

__device__ __forceinline__ int reflect_idx(int i, int n) {
    i = (i < 0) ? -i : i;
    i = (i >= n) ? (2 * n - 2 - i) : i;
    return i;
}

__device__ __forceinline__ unsigned short umin16(unsigned short a, unsigned short b) {
    return a < b ? a : b;
}

// clip((v+1)/2, 0, 0.1) then f32->bf16 RNE. Non-negative, so bf16 bit pattern
// order == numeric order -> window mins run as u16 integer mins.
__device__ __forceinline__ unsigned short map_bf16(float v) {
    float m = fminf(fmaxf(fmaf(v, 0.5f, 0.5f), 0.0f), 0.1f);
    unsigned int u = __float_as_uint(m);
    return (unsigned short)((u + 0x7fffu + ((u >> 16) & 1u)) >> 16);
}

__device__ __forceinline__ float bf16_f32(unsigned short x) {
    return __uint_as_float(((unsigned int)x) << 16);
}

__device__ __forceinline__ void dark_tile(const float* __restrict__ X,
                                          unsigned short* __restrict__ cmin,
                                          unsigned short* __restrict__ vm,
                                          int tid, int r0g, int c0g, bool fastcol,
                                          float (&o)[16]) {
    // ---- Phase 1: global -> channel-min -> map -> bf16 -> cmin[78 rows][slots 0..79]
    // Physical slot p holds logical col p-1 (global col c0g + p - 1); slots 0,79 = pad.
    #pragma unroll
    for (int i = 0; i < P1_ITERS; ++i) {
        int t = tid + i * BDIM;
        t = t < (P1_TASKS - 1) ? t : (P1_TASKS - 1);   // tail: duplicate last task (benign)
        int row = (unsigned)t / 20u;
        int g = t - row * 20;
        int gr = reflect_idx(r0g + row, IMG);
        const float* rp = X + (size_t)gr * IMG;
        unsigned short w[4];
        if (fastcol) {
            const float* p = rp + (c0g - 1 + 4 * g);   // 16B-aligned for interior blocks
            f4 a = *(const f4*)p;
            f4 b = *(const f4*)(p + HW);
            f4 c = *(const f4*)(p + 2 * HW);
            #pragma unroll
            for (int k = 0; k < 4; ++k)
                w[k] = map_bf16(fminf(a[k], fminf(b[k], c[k])));
        } else {
            #pragma unroll
            for (int k = 0; k < 4; ++k) {
                int gc = reflect_idx(c0g - 1 + 4 * g + k, IMG);
                float v = fminf(rp[gc], fminf(rp[HW + gc], rp[2 * HW + gc]));
                w[k] = map_bf16(v);
            }
        }
        uint2 pk;
        pk.x = (unsigned)w[0] | ((unsigned)w[1] << 16);
        pk.y = (unsigned)w[2] | ((unsigned)w[3] << 16);
        *(uint2*)&cmin[row * CSTR + 4 * g] = pk;       // byte 168*row+8*g: 8B-aligned
    }
    __syncthreads();

    // ---- Phase 2: vertical 15-min (u16), cmin -> vm[64][cols 0..77]
    #pragma unroll
    for (int b = 0; b < 2; ++b) {
        int t = tid + b * BDIM;
        if (t < IN_T * 4) {
            int col = (unsigned)t % (unsigned)IN_T;
            int rr0 = ((unsigned)t / (unsigned)IN_T) * 16;
            const unsigned short* cp = cmin + (col + 1);
            unsigned short s[15];
            #pragma unroll
            for (int j = 0; j < 15; ++j) s[j] = cp[(rr0 + j) * CSTR];
            #pragma unroll
            for (int j = 13; j >= 0; --j) s[j] = umin16(s[j], s[j + 1]);
            unsigned short* vp = vm + col;
            vp[rr0 * VSTR] = s[0];
            unsigned short f = cp[(rr0 + 15) * CSTR];
            #pragma unroll
            for (int i2 = 1; i2 <= 14; ++i2) {
                vp[(rr0 + i2) * VSTR] = umin16(s[i2], f);
                f = umin16(f, cp[(rr0 + 15 + i2) * CSTR]);
            }
            vp[(rr0 + 15) * VSTR] = f;
        }
    }
    __syncthreads();

    // ---- Phase 3: horizontal 15-min (u16) from vm, 16 outputs/thread
    {
        int row = tid >> 2, k = tid & 3;
        const unsigned int* vr = (const unsigned int*)(vm + row * VSTR) + 8 * k;
        unsigned short x[32];
        #pragma unroll
        for (int j = 0; j < 16; ++j) {
            unsigned int d = vr[j];
            x[2 * j] = (unsigned short)d;
            x[2 * j + 1] = (unsigned short)(d >> 16);
        }
        unsigned short s[15];
        #pragma unroll
        for (int j = 0; j < 15; ++j) s[j] = x[j];
        #pragma unroll
        for (int j = 13; j >= 0; --j) s[j] = umin16(s[j], s[j + 1]);
        o[0] = bf16_f32(s[0]);
        unsigned short f = x[15];
        #pragma unroll
        for (int i2 = 1; i2 <= 14; ++i2) {
            o[i2] = bf16_f32(umin16(s[i2], f));
            f = umin16(f, x[15 + i2]);
        }
        o[15] = bf16_f32(f);
    }
}

__global__ __launch_bounds__(BDIM, 4)
void dcl_kernel(const float* __restrict__ real, const float* __restrict__ fake,
                float* __restrict__ ws) {
    __shared__ __align__(8) unsigned short cmin[IN_T * CSTR];  // 13.1 KB
    __shared__ __align__(8) unsigned short vm[TILE * VSTR];    // 10.5 KB
    __shared__ float red[BDIM / 64];

    const int tid = threadIdx.x;
    const int r0g = blockIdx.y * TILE - HALO;
    const int c0g = blockIdx.x * TILE - HALO;
    const bool fastcol = (c0g >= 1) && (c0g + 79 <= IMG);
    const size_t ib = (size_t)blockIdx.z * 3 * HW;

    float o_r[16], o_f[16];
    dark_tile(real + ib, cmin, vm, tid, r0g, c0g, fastcol, o_r);
    // no barrier needed: fake's phase-1 writes cmin (guarded by its own barrier
    // before phase 2); vm reads of phase 3 complete before that barrier releases.
    dark_tile(fake + ib, cmin, vm, tid, r0g, c0g, fastcol, o_f);

    float acc = 0.f;
    #pragma unroll
    for (int i = 0; i < 16; ++i) {
        float d = o_r[i] - o_f[i];
        acc += d * d;
    }
    #pragma unroll
    for (int off = 32; off >= 1; off >>= 1)
        acc += __shfl_xor(acc, off, 64);
    if ((tid & 63) == 0) red[tid >> 6] = acc;
    __syncthreads();
    if (tid == 0) {
        // per-block partial -> workspace; NO same-address atomic (that was the
        // ~56 us floor: 1024 serialized device-scope RMWs on one address)
        int bid = blockIdx.x + 8 * (blockIdx.y + 8 * blockIdx.z);
        ws[bid] = red[0] + red[1] + red[2] + red[3];
    }
}

__global__ __launch_bounds__(256)
void reduce_kernel(const float* __restrict__ ws, float* __restrict__ out) {
    __shared__ float red[4];
    int tid = threadIdx.x;
    float a = ws[tid] + ws[tid + 256] + ws[tid + 512] + ws[tid + 768];
    #pragma unroll
    for (int off = 32; off >= 1; off >>= 1)
        a += __shfl_xor(a, off, 64);
    if ((tid & 63) == 0) red[tid >> 6] = a;
    __syncthreads();
    if (tid == 0)
        out[0] = (red[0] + red[1] + red[2] + red[3]) * (1.0f / NPIX);
}

extern "C" void kernel_launch(void* const* d_in, const int* in_sizes, int n_in,
                              void* d_out, int out_size, void* d_ws, size_t ws_size,
                              hipStream_t stream) {
    const float* real = (const float*)d_in[0];
    const float* fake = (const float*)d_in[1];
    float* ws = (float*)d_ws;
    float* out = (float*)d_out;
    dim3 grid(IMG / TILE, IMG / TILE, 16);
    dcl_kernel<<<grid, BDIM, 0, stream>>>(real, fake, ws);
    reduce_kernel<<<1, 256, 0, stream>>>(ws, out);
}

// Round 5
// 132.849 us; speedup vs baseline: 1.3079x; 1.0549x over previous
//
#include <hip/hip_runtime.h>

#define BDIM 256
#define TILE 64
#define HALO 7
#define IN_T 78            // halo'd tile rows/cols
#define CSTR 84            // cmin row stride (ushort): 168 B rows, 8B-aligned
#define VSTR 82            // vm row stride (ushort): 164 B = 41 dwords, gcd(41,32)=1
#define IMG 512
#define HW (IMG * IMG)
#define NPIX (16.0f * 512.0f * 512.0f)
#define P1_TASKS (IN_T * 20)   // 78 rows x 20 float4-groups = 1560
#define NBLK 1024

typedef float f4 __attribute__((ext_vector_type(4)));

__device__ __forceinline__ int reflect_idx(int i, int n) {
    i = (i < 0) ? -i : i;
    i = (i >= n) ? (2 * n - 2 - i) : i;
    return i;
}

__device__ __forceinline__ unsigned short umin16(unsigned short a, unsigned short b) {
    return a < b ? a : b;
}

// clip((v+1)/2, 0, 0.1) then f32->bf16 RNE. Non-negative => u16 order == numeric.
__device__ __forceinline__ unsigned short map_bf16(float v) {
    float m = fminf(fmaxf(fmaf(v, 0.5f, 0.5f), 0.0f), 0.1f);
    unsigned int u = __float_as_uint(m);
    return (unsigned short)((u + 0x7fffu + ((u >> 16) & 1u)) >> 16);
}

__device__ __forceinline__ float bf16_f32(unsigned short x) {
    return __uint_as_float(((unsigned int)x) << 16);
}

// ---- Phase 2: vertical 15-min (u16), cm -> vm
__device__ __forceinline__ void phase2(const unsigned short* __restrict__ cm,
                                       unsigned short* __restrict__ vm, int tid) {
    #pragma unroll
    for (int b = 0; b < 2; ++b) {
        int t = tid + b * BDIM;
        if (t < IN_T * 4) {
            int col = (unsigned)t % (unsigned)IN_T;
            int rr0 = ((unsigned)t / (unsigned)IN_T) * 16;
            const unsigned short* cp = cm + (col + 1);
            unsigned short s[15];
            #pragma unroll
            for (int j = 0; j < 15; ++j) s[j] = cp[(rr0 + j) * CSTR];
            #pragma unroll
            for (int j = 13; j >= 0; --j) s[j] = umin16(s[j], s[j + 1]);
            unsigned short* vp = vm + col;
            vp[rr0 * VSTR] = s[0];
            unsigned short f = cp[(rr0 + 15) * CSTR];
            #pragma unroll
            for (int i2 = 1; i2 <= 14; ++i2) {
                vp[(rr0 + i2) * VSTR] = umin16(s[i2], f);
                f = umin16(f, cp[(rr0 + 15 + i2) * CSTR]);
            }
            vp[(rr0 + 15) * VSTR] = f;
        }
    }
}

// ---- Phase 3: horizontal 15-min (u16) from vm -> 16 f32 regs
__device__ __forceinline__ void phase3(const unsigned short* __restrict__ vm,
                                       int tid, float (&o)[16]) {
    int row = tid >> 2, k = tid & 3;
    const unsigned int* vr = (const unsigned int*)(vm + row * VSTR) + 8 * k;
    unsigned short x[32];
    #pragma unroll
    for (int j = 0; j < 16; ++j) {
        unsigned int d = vr[j];
        x[2 * j] = (unsigned short)d;
        x[2 * j + 1] = (unsigned short)(d >> 16);
    }
    unsigned short s[15];
    #pragma unroll
    for (int j = 0; j < 15; ++j) s[j] = x[j];
    #pragma unroll
    for (int j = 13; j >= 0; --j) s[j] = umin16(s[j], s[j + 1]);
    o[0] = bf16_f32(s[0]);
    unsigned short f = x[15];
    #pragma unroll
    for (int i2 = 1; i2 <= 14; ++i2) {
        o[i2] = bf16_f32(umin16(s[i2], f));
        f = umin16(f, x[15 + i2]);
    }
    o[15] = bf16_f32(f);
}

__global__ __launch_bounds__(BDIM, 4)
void dcl_kernel(const float* __restrict__ real, const float* __restrict__ fake,
                float* __restrict__ ws) {
    __shared__ __align__(8) unsigned short cmr[IN_T * CSTR];  // 13.1 KB
    __shared__ __align__(8) unsigned short cmf[IN_T * CSTR];  // 13.1 KB
    __shared__ __align__(8) unsigned short vm[TILE * VSTR];   // 10.5 KB (reused r then f)
    __shared__ float red[BDIM / 64];

    const int tid = threadIdx.x;
    // XCD-panel swizzle: hw assigns bid%8 -> XCD (round-robin). Give each XCD a
    // 4x2-tile panel per image so halo-sharing neighbors co-reside in one L2.
    const int bid = blockIdx.x;
    const int xcd = bid & 7;
    const int s_ = bid >> 3;            // 0..127
    const int z  = s_ & 15;             // image
    const int tt = s_ >> 4;             // 0..7 tile-in-panel
    const int bx = (xcd & 1) * 4 + (tt & 3);
    const int by = (xcd >> 1) * 2 + (tt >> 2);

    const int r0g = by * TILE - HALO;
    const int c0g = bx * TILE - HALO;
    const bool fastcol = (bx >= 1) && (bx <= 6);   // c0g-1 = 64bx-8: >=0, %4==0, +80<=512
    const size_t ib = (size_t)z * 3 * HW;
    const float* __restrict__ Rb = real + ib;
    const float* __restrict__ Fb = fake + ib;

    // ---- Phase 1, both images, software-pipelined (double-buffered regs)
    f4 bR[2][3], bF[2][3];

    auto load_i = [&](int i, f4 (&R3)[3], f4 (&F3)[3]) {
        int t = tid + i * BDIM;
        t = t < (P1_TASKS - 1) ? t : (P1_TASKS - 1);   // tail clamp (benign dup)
        int row = (unsigned)t / 20u;
        int g = t - row * 20;
        int gr = reflect_idx(r0g + row, IMG);
        const float* rpR = Rb + (size_t)gr * IMG;
        const float* rpF = Fb + (size_t)gr * IMG;
        if (fastcol) {
            const float* pR = rpR + (c0g - 1 + 4 * g);   // 16B-aligned
            const float* pF = rpF + (c0g - 1 + 4 * g);
            R3[0] = *(const f4*)pR;
            R3[1] = *(const f4*)(pR + HW);
            R3[2] = *(const f4*)(pR + 2 * HW);
            F3[0] = *(const f4*)pF;
            F3[1] = *(const f4*)(pF + HW);
            F3[2] = *(const f4*)(pF + 2 * HW);
        } else {
            #pragma unroll
            for (int k = 0; k < 4; ++k) {
                int gc = reflect_idx(c0g - 1 + 4 * g + k, IMG);
                R3[0][k] = rpR[gc]; R3[1][k] = rpR[HW + gc]; R3[2][k] = rpR[2 * HW + gc];
                F3[0][k] = rpF[gc]; F3[1][k] = rpF[HW + gc]; F3[2][k] = rpF[2 * HW + gc];
            }
        }
    };

    auto consume_i = [&](int i, const f4 (&R3)[3], const f4 (&F3)[3]) {
        int t = tid + i * BDIM;
        t = t < (P1_TASKS - 1) ? t : (P1_TASKS - 1);
        int row = (unsigned)t / 20u;
        int g = t - row * 20;
        unsigned short wr[4], wf[4];
        #pragma unroll
        for (int k = 0; k < 4; ++k) {
            wr[k] = map_bf16(fminf(R3[0][k], fminf(R3[1][k], R3[2][k])));
            wf[k] = map_bf16(fminf(F3[0][k], fminf(F3[1][k], F3[2][k])));
        }
        uint2 pr, pf;
        pr.x = (unsigned)wr[0] | ((unsigned)wr[1] << 16);
        pr.y = (unsigned)wr[2] | ((unsigned)wr[3] << 16);
        pf.x = (unsigned)wf[0] | ((unsigned)wf[1] << 16);
        pf.y = (unsigned)wf[2] | ((unsigned)wf[3] << 16);
        *(uint2*)&cmr[row * CSTR + 4 * g] = pr;
        *(uint2*)&cmf[row * CSTR + 4 * g] = pf;
    };

    load_i(0, bR[0], bF[0]);
    #pragma unroll
    for (int i = 0; i < 7; ++i) {
        if (i < 6) load_i(i + 1, bR[(i + 1) & 1], bF[(i + 1) & 1]);
        consume_i(i, bR[i & 1], bF[i & 1]);
    }
    __syncthreads();

    float o_r[16], o_f[16];
    phase2(cmr, vm, tid);
    __syncthreads();
    phase3(vm, tid, o_r);
    __syncthreads();                 // WAR: vm reads done before fake overwrites
    phase2(cmf, vm, tid);
    __syncthreads();
    phase3(vm, tid, o_f);

    float acc = 0.f;
    #pragma unroll
    for (int i = 0; i < 16; ++i) {
        float d = o_r[i] - o_f[i];
        acc += d * d;
    }
    #pragma unroll
    for (int off = 32; off >= 1; off >>= 1)
        acc += __shfl_xor(acc, off, 64);
    if ((tid & 63) == 0) red[tid >> 6] = acc;
    __syncthreads();
    if (tid == 0)
        ws[bid] = red[0] + red[1] + red[2] + red[3];
}

__global__ __launch_bounds__(256)
void reduce_kernel(const float* __restrict__ ws, float* __restrict__ out) {
    __shared__ float red[4];
    int tid = threadIdx.x;
    float a = ws[tid] + ws[tid + 256] + ws[tid + 512] + ws[tid + 768];
    #pragma unroll
    for (int off = 32; off >= 1; off >>= 1)
        a += __shfl_xor(a, off, 64);
    if ((tid & 63) == 0) red[tid >> 6] = a;
    __syncthreads();
    if (tid == 0)
        out[0] = (red[0] + red[1] + red[2] + red[3]) * (1.0f / NPIX);
}

extern "C" void kernel_launch(void* const* d_in, const int* in_sizes, int n_in,
                              void* d_out, int out_size, void* d_ws, size_t ws_size,
                              hipStream_t stream) {
    const float* real = (const float*)d_in[0];
    const float* fake = (const float*)d_in[1];
    float* ws = (float*)d_ws;
    float* out = (float*)d_out;
    dcl_kernel<<<dim3(NBLK), BDIM, 0, stream>>>(real, fake, ws);
    reduce_kernel<<<1, 256, 0, stream>>>(ws, out);
}